// Round 13
// baseline (81.713 us; speedup 1.0000x reference)
//
#include <hip/hip_runtime.h>
#include <hip/hip_bf16.h>

#define B_GRAPHS 512
#define NPG 87
#define NPGP 96
#define EPG 1392
#define NN (B_GRAPHS*NPG)        // 44544
#define NE (B_GRAPHS*EPG)        // 712704
#define HID 256
#define EMBD 768
#define ADJSZ (B_GRAPHS*NPG*NPG) // 3875328
#define HSTR 264                 // h layout stride (96 rows x 256 feats)
#define TSTR 104                 // Tt layout stride (256 rows x 96 nodes)
#define ASTRF 92                 // adj f32 staging stride
#define BUF_ELEMS 26624          // max(96*HSTR, 256*TSTR) ushorts = 53248 B

typedef __attribute__((ext_vector_type(8))) short bf16x8;
typedef __attribute__((ext_vector_type(4))) float f32x4;

// native f32->bf16 (RNE); compiler pairs adjacent casts into v_cvt_pk_bf16_f32
__device__ __forceinline__ ushort f2b(float f) {
    __hip_bfloat16 h = __float2bfloat16(f);
    ushort u;
    __builtin_memcpy(&u, &h, 2);
    return u;
}
__device__ __forceinline__ ushort4 cvt4(f32x4 v) {
    ushort4 o; o.x = f2b(v[0]); o.y = f2b(v[1]); o.z = f2b(v[2]); o.w = f2b(v[3]);
    return o;
}

// upper-triangle tile rank t in [0,21) -> (i,j), i<=j<6
__device__ __forceinline__ void unrank21(int t, int& i, int& j) {
    i = (t >= 20) ? 5 : (t >= 18) ? 4 : (t >= 15) ? 3 : (t >= 11) ? 2 : (t >= 6) ? 1 : 0;
    int off = (i == 5) ? 20 : (i == 4) ? 18 : (i == 3) ? 15 : (i == 2) ? 11 : (i == 1) ? 6 : 0;
    j = i + (t - off);
}

// ---- W [K][256] f32 -> WTs in wave-fragment order ----
__global__ __launch_bounds__(256) void k_cast_wt(const float* __restrict__ W1,
                                                 const float* __restrict__ W2,
                                                 const float* __restrict__ W3,
                                                 ushort* __restrict__ WTs1,
                                                 ushort* __restrict__ WTs2,
                                                 ushort* __restrict__ WTs3) {
    int y = blockIdx.y;
    const float* W = (y == 0) ? W1 : (y == 1) ? W2 : W3;
    ushort* WTs = (y == 0) ? WTs1 : (y == 1) ? WTs2 : WTs3;
    int K   = (y == 0) ? NPG : HID;
    int NKS = (y == 0) ? 3 : 8;
    int total = 4*NKS*4*64*8;                 // 256*Kp
    int idx = blockIdx.x*256 + threadIdx.x;
    if (idx >= total) return;
    int e    = idx & 7;
    int lane = (idx >> 3) & 63;
    int j    = (idx >> 9) & 3;
    int rest = idx >> 11;
    int ks   = rest % NKS;
    int fg   = rest / NKS;
    int row = fg*64 + j*16 + (lane & 15);     // 0..255
    int k   = ks*32 + (lane >> 4)*8 + e;      // 0..Kp-1
    WTs[idx] = (k < K) ? f2b(W[(size_t)k*HID + row]) : (ushort)0;
}

// ---- dense normalized adjacency, wave-fragment order, deterministic int accum ----
__global__ __launch_bounds__(256) void k_buildA(const int* __restrict__ src,
                                                const int* __restrict__ dst,
                                                const float* __restrict__ ew,
                                                ushort* __restrict__ AbS) {
    __shared__ int   sAi[NPGP*NPGP];   // A accum, scale 2^24
    __shared__ int   sdegi[NPGP];      // deg accum, scale 2^20
    __shared__ float sdi[NPGP];
    int g = blockIdx.x, tid = threadIdx.x;
    for (int i = tid; i < NPGP*NPGP; i += 256) sAi[i] = 0;
    if (tid < NPGP) sdegi[tid] = 0;
    int base = g*NPG;
    int sl[6], dl[6]; float wv[6];
    #pragma unroll
    for (int it = 0; it < 6; ++it) {
        int eo = tid + it*256;
        bool v = (eo < EPG);
        int e = g*EPG + (v ? eo : 0);
        sl[it] = src[e] - base;
        dl[it] = dst[e] - base;
        wv[it] = v ? ew[e] : 0.f;
    }
    __syncthreads();
    #pragma unroll
    for (int it = 0; it < 6; ++it)
        atomicAdd(&sdegi[dl[it]], (int)rintf(wv[it]*1048576.0f));
    __syncthreads();
    if (tid < NPGP) {
        float deg = 1.0f + (float)sdegi[tid]*(1.0f/1048576.0f);   // +1 self-loop
        sdi[tid] = rsqrtf(deg);
    }
    __syncthreads();
    #pragma unroll
    for (int it = 0; it < 6; ++it) {
        float v = sdi[sl[it]]*wv[it]*sdi[dl[it]];
        atomicAdd(&sAi[dl[it]*NPGP + sl[it]], (int)rintf(v*16777216.0f));
    }
    __syncthreads();
    if (tid < NPG) {                   // diagonal self-loop term (single writer)
        float di = sdi[tid];
        sAi[tid*NPGP + tid] += (int)rintf(di*di*16777216.0f);
    }
    __syncthreads();
    ushort* outp = AbS + (size_t)g*NPGP*NPGP;
    for (int i = tid; i < NPGP*NPGP; i += 256) {
        int e    = i & 7;
        int lane = (i >> 3) & 63;
        int t    = i >> 9;             // 0..17
        int j  = t % 3;
        int ks = (t / 3) % 3;
        int mg = t / 9;
        int row = mg*48 + j*16 + (lane & 15);
        int col = ks*32 + (lane >> 4)*8 + e;
        outp[i] = f2b((float)sAi[row*NPGP + col]*(1.0f/16777216.0f));
    }
}

// ---- one GCN layer, fully LDS-resident; A fragments held in registers ----
template<int NKS>
__device__ __forceinline__ void do_layer(ushort* buf,
                                         const ushort* __restrict__ WTs,
                                         const float* __restrict__ bias,
                                         const bf16x8 (&aReg)[3][3],
                                         float* sPool,
                                         int layer, int wave, int lane) {
    const int l15 = lane & 15, q = lane >> 4, lk = q*8;
    const int mg = wave >> 2, fg = wave & 3;

    // ---- S1: T = H @ W ----
    f32x4 acc1[3][4] = {};
    #pragma unroll
    for (int ks = 0; ks < NKS; ++ks) {
        bf16x8 af[3], bfr[4];
        #pragma unroll
        for (int i = 0; i < 3; ++i)
            af[i] = *(const bf16x8*)&buf[(mg*48 + i*16 + l15)*HSTR + ks*32 + lk];
        #pragma unroll
        for (int j = 0; j < 4; ++j)
            bfr[j] = *(const bf16x8*)&WTs[(size_t)(((fg*NKS + ks)*4 + j)*64 + lane)*8];
        #pragma unroll
        for (int i = 0; i < 3; ++i)
            #pragma unroll
            for (int j = 0; j < 4; ++j)
                acc1[i][j] = __builtin_amdgcn_mfma_f32_16x16x32_bf16(af[i], bfr[j], acc1[i][j], 0, 0, 0);
    }
    __syncthreads();   // (a) all h reads complete
    // ---- S2: write Tt[feat][node] over buf ----
    #pragma unroll
    for (int i = 0; i < 3; ++i)
        #pragma unroll
        for (int j = 0; j < 4; ++j)
            *(ushort4*)&buf[(fg*64 + j*16 + l15)*TSTR + mg*48 + i*16 + q*4] = cvt4(acc1[i][j]);
    __syncthreads();   // (b) Tt ready

    // ---- S3: E = A @ T (A fragments from registers) ----
    f32x4 acc2[4][3] = {};
    #pragma unroll
    for (int ks = 0; ks < 3; ++ks) {
        bf16x8 af2[4];
        #pragma unroll
        for (int i = 0; i < 4; ++i)
            af2[i] = *(const bf16x8*)&buf[(fg*64 + i*16 + l15)*TSTR + ks*32 + lk];
        #pragma unroll
        for (int i = 0; i < 4; ++i)
            #pragma unroll
            for (int j = 0; j < 3; ++j)
                acc2[i][j] = __builtin_amdgcn_mfma_f32_16x16x32_bf16(af2[i], aReg[ks][j], acc2[i][j], 0, 0, 0);
    }
    __syncthreads();   // (c) Tt reads complete

    // ---- S4: h = relu(E + b) over buf + pool partials into sPool ----
    const int loff = layer << 8;
    #pragma unroll
    for (int i = 0; i < 4; ++i) {
        int featb = fg*64 + i*16 + q*4;
        float4 bv = *(const float4*)&bias[featb];
        f32x4 psum = {};
        #pragma unroll
        for (int j = 0; j < 3; ++j) {
            int d = mg*48 + j*16 + l15;
            f32x4 v;
            v[0] = fmaxf(acc2[i][j][0] + bv.x, 0.f);
            v[1] = fmaxf(acc2[i][j][1] + bv.y, 0.f);
            v[2] = fmaxf(acc2[i][j][2] + bv.z, 0.f);
            v[3] = fmaxf(acc2[i][j][3] + bv.w, 0.f);
            if (d >= NPG) { v[0] = 0.f; v[1] = 0.f; v[2] = 0.f; v[3] = 0.f; }
            *(ushort4*)&buf[d*HSTR + featb] = cvt4(v);
            psum += v;
        }
        float s0 = psum[0], s1 = psum[1], s2 = psum[2], s3 = psum[3];
        #pragma unroll
        for (int m = 1; m < 16; m <<= 1) {
            s0 += __shfl_xor(s0, m); s1 += __shfl_xor(s1, m);
            s2 += __shfl_xor(s2, m); s3 += __shfl_xor(s3, m);
        }
        if (l15 == 0)
            *(float4*)&sPool[mg*EMBD + loff + featb] = make_float4(s0, s1, s2, s3);
    }
    __syncthreads();   // (d) h ready (Gram + next S1 read after this)
}

// ---- symmetric Gram: 21 upper-triangle tiles, consecutive ranges per wave ----
__device__ __forceinline__ void do_gram(const ushort* buf, int wave, int lane,
                                        f32x4 (&gacc)[3]) {
    const int l15 = lane & 15, lk = (lane >> 4)*8;
    const int start = (wave < 5) ? wave*3 : 15 + (wave - 5)*2;
    const int count = (wave < 5) ? 3 : 2;
    int ra0, rb0, ra1, rb1, ra2, rb2;
    unrank21(start,     ra0, rb0);
    unrank21(start + 1, ra1, rb1);
    unrank21(count > 2 ? start + 2 : start, ra2, rb2);  // dummy=slot0 if unused
    #pragma unroll
    for (int ks = 0; ks < 8; ++ks) {
        bf16x8 a0 = *(const bf16x8*)&buf[(ra0*16 + l15)*HSTR + ks*32 + lk];
        bf16x8 b0 = *(const bf16x8*)&buf[(rb0*16 + l15)*HSTR + ks*32 + lk];
        gacc[0] = __builtin_amdgcn_mfma_f32_16x16x32_bf16(a0, b0, gacc[0], 0, 0, 0);
        bf16x8 a1 = *(const bf16x8*)&buf[(ra1*16 + l15)*HSTR + ks*32 + lk];
        bf16x8 b1 = *(const bf16x8*)&buf[(rb1*16 + l15)*HSTR + ks*32 + lk];
        gacc[1] = __builtin_amdgcn_mfma_f32_16x16x32_bf16(a1, b1, gacc[1], 0, 0, 0);
        if (count > 2) {
            bf16x8 a2 = *(const bf16x8*)&buf[(ra2*16 + l15)*HSTR + ks*32 + lk];
            bf16x8 b2 = *(const bf16x8*)&buf[(rb2*16 + l15)*HSTR + ks*32 + lk];
            gacc[2] = __builtin_amdgcn_mfma_f32_16x16x32_bf16(a2, b2, gacc[2], 0, 0, 0);
        }
    }
}

// ---- mega kernel: 3 layers + pool/logits + decoder, one block per graph ----
__global__ __launch_bounds__(512, 4) void k_mega(const float* __restrict__ x,
                                                 const ushort* __restrict__ AbS,
                                                 const ushort* __restrict__ WTs1,
                                                 const ushort* __restrict__ WTs2,
                                                 const ushort* __restrict__ WTs3,
                                                 const float* __restrict__ b1,
                                                 const float* __restrict__ b2,
                                                 const float* __restrict__ b3,
                                                 const float* __restrict__ Wc,
                                                 const float* __restrict__ bc,
                                                 float* __restrict__ outp) {
    __shared__ ushort buf[BUF_ELEMS];
    __shared__ float  sPool[2*EMBD];
    const int g = blockIdx.x, tid = threadIdx.x;
    const int wave = tid >> 6, lane = tid & 63;
    const int l15 = lane & 15, q = lane >> 4;
    const int mg = wave >> 2;

    // A fragments for this wave's mg-half: 9 x 16B, wave-uniform, coalesced
    const ushort* AbG = AbS + (size_t)g*NPGP*NPGP;
    bf16x8 aReg[3][3];
    #pragma unroll
    for (int ks = 0; ks < 3; ++ks)
        #pragma unroll
        for (int j = 0; j < 3; ++j)
            aReg[ks][j] = *(const bf16x8*)&AbG[(size_t)(((mg*3 + ks)*3 + j)*64 + lane)*8];

    // stage x into h-layout (rows 0..95 x cols 0..95, zero-padded)
    for (int idx = tid; idx < NPGP*NPGP; idx += 512) {
        int r = idx / NPGP, c = idx - r*NPGP;
        float v = (r < NPG && c < NPG) ? x[((size_t)g*NPG + r)*NPG + c] : 0.f;
        buf[r*HSTR + c] = f2b(v);
    }
    __syncthreads();

    f32x4 gacc[3] = {};

    do_layer<3>(buf, WTs1, b1, aReg, sPool, 0, wave, lane);
    do_gram(buf, wave, lane, gacc);
    do_layer<8>(buf, WTs2, b2, aReg, sPool, 1, wave, lane);
    do_gram(buf, wave, lane, gacc);
    do_layer<8>(buf, WTs3, b3, aReg, sPool, 2, wave, lane);
    do_gram(buf, wave, lane, gacc);

    // ---- epilogue ----
    __syncthreads();                       // all Gram/S1 reads of buf complete
    float* fbuf = (float*)buf;             // adj staging [87][ASTRF] + reduce scratch
    {
        const int start = (wave < 5) ? wave*3 : 15 + (wave - 5)*2;
        const int count = (wave < 5) ? 3 : 2;
        #pragma unroll
        for (int s = 0; s < 3; ++s) {
            if (s < count) {
                int ti, tj;
                unrank21(start + s, ti, tj);
                int jj = tj*16 + l15;
                #pragma unroll
                for (int r = 0; r < 4; ++r) {
                    int ii = ti*16 + q*4 + r;
                    float v = fmaxf(gacc[s][r], 0.f);
                    if (ii < NPG && jj < NPG) {
                        fbuf[ii*ASTRF + jj] = v;
                        if (ti != tj) fbuf[jj*ASTRF + ii] = v;
                    }
                }
            }
        }
    }
    // logits partials (sPool stable since layer-3 barrier (d))
    float p0 = 0.f, p1 = 0.f;
    #pragma unroll
    for (int k2 = 0; k2 < 3; ++k2) {
        int c = tid + k2*512;
        int f = (c >= EMBD) ? c - EMBD : c;
        float v = sPool[c];
        p0 += v * Wc[f*2 + 0];
        p1 += v * Wc[f*2 + 1];
    }
    #pragma unroll
    for (int m = 1; m < 64; m <<= 1) { p0 += __shfl_xor(p0, m); p1 += __shfl_xor(p1, m); }
    if (lane == 0) { fbuf[8064 + wave*2] = p0; fbuf[8064 + wave*2 + 1] = p1; }
    __syncthreads();

    // coalesced adj copy-out (30.3 KB contiguous per graph)
    float* og = outp + (size_t)g*NPG*NPG;
    for (int idx = tid; idx < NPG*NPG; idx += 512) {
        int r = idx / NPG, cc = idx - r*NPG;
        og[idx] = fbuf[r*ASTRF + cc];
    }
    if (tid == 0) {
        float q0 = 0.f, q1 = 0.f;
        #pragma unroll
        for (int w = 0; w < 8; ++w) { q0 += fbuf[8064 + w*2]; q1 += fbuf[8064 + w*2 + 1]; }
        outp[ADJSZ + (size_t)g*2 + 0] = q0*(1.0f/87.0f) + bc[0];
        outp[ADJSZ + (size_t)g*2 + 1] = q1*(1.0f/87.0f) + bc[1];
    }
}

extern "C" void kernel_launch(void* const* d_in, const int* in_sizes, int n_in,
                              void* d_out, int out_size, void* d_ws, size_t ws_size,
                              hipStream_t stream) {
    const float* x   = (const float*)d_in[0];
    const int*   ei  = (const int*)d_in[1];
    const float* ew  = (const float*)d_in[2];
    const float* W1  = (const float*)d_in[4];
    const float* b1  = (const float*)d_in[5];
    const float* W2  = (const float*)d_in[6];
    const float* b2  = (const float*)d_in[7];
    const float* W3  = (const float*)d_in[8];
    const float* b3  = (const float*)d_in[9];
    const float* Wc  = (const float*)d_in[10];
    const float* bc  = (const float*)d_in[11];
    float* outp = (float*)d_out;

    char* ws = (char*)d_ws;
    ushort* AbS  = (ushort*)ws;  ws += (size_t)B_GRAPHS*NPGP*NPGP*2;
    ushort* WTs1 = (ushort*)ws;  ws += (size_t)HID*NPGP*2;
    ushort* WTs2 = (ushort*)ws;  ws += (size_t)HID*HID*2;
    ushort* WTs3 = (ushort*)ws;  ws += (size_t)HID*HID*2;

    const int* srcp = ei;
    const int* dstp = ei + NE;

    k_cast_wt<<<dim3(256,3), 256, 0, stream>>>(W1, W2, W3, WTs1, WTs2, WTs3);
    k_buildA <<<B_GRAPHS, 256, 0, stream>>>(srcp, dstp, ew, AbS);
    k_mega   <<<B_GRAPHS, 512, 0, stream>>>(x, AbS, WTs1, WTs2, WTs3,
                                            b1, b2, b3, Wc, bc, outp);
}

// Round 14
// 64.310 us; speedup vs baseline: 1.2706x; 1.2706x over previous
//
#include <hip/hip_runtime.h>
#include <hip/hip_bf16.h>

#define B_GRAPHS 512
#define NPG 87
#define NPGP 96
#define EPG 1392
#define NN (B_GRAPHS*NPG)        // 44544
#define NE (B_GRAPHS*EPG)        // 712704
#define HID 256
#define EMBD 768
#define ADJSZ (B_GRAPHS*NPG*NPG) // 3875328
#define HSTR 264                 // h layout stride (96 rows x 256 feats)
#define TSTR 104                 // Tt layout stride (256 rows x 96 nodes)
#define ASTRF 92                 // adj f32 staging stride
#define BUF_ELEMS 26624          // max(96*HSTR, 256*TSTR) ushorts = 53248 B
#define SA_ELEMS (NPGP*NPGP)     // 9216 ushorts = 18432 B
#define LDS_TOTAL (BUF_ELEMS*2 + SA_ELEMS*2 + 2*EMBD*4)   // 77824 B

typedef __attribute__((ext_vector_type(8))) short bf16x8;
typedef __attribute__((ext_vector_type(4))) float f32x4;

// native f32->bf16 (RNE); compiler pairs adjacent casts into v_cvt_pk_bf16_f32
__device__ __forceinline__ ushort f2b(float f) {
    __hip_bfloat16 h = __float2bfloat16(f);
    ushort u;
    __builtin_memcpy(&u, &h, 2);
    return u;
}
__device__ __forceinline__ ushort4 cvt4(f32x4 v) {
    ushort4 o; o.x = f2b(v[0]); o.y = f2b(v[1]); o.z = f2b(v[2]); o.w = f2b(v[3]);
    return o;
}

// upper-triangle tile rank t in [0,21) -> (i,j), i<=j<6
__device__ __forceinline__ void unrank21(int t, int& i, int& j) {
    i = (t >= 20) ? 5 : (t >= 18) ? 4 : (t >= 15) ? 3 : (t >= 11) ? 2 : (t >= 6) ? 1 : 0;
    int off = (i == 5) ? 20 : (i == 4) ? 18 : (i == 3) ? 15 : (i == 2) ? 11 : (i == 1) ? 6 : 0;
    j = i + (t - off);
}

// ---- W [K][256] f32 -> WTs in wave-fragment order ----
__global__ __launch_bounds__(256) void k_cast_wt(const float* __restrict__ W1,
                                                 const float* __restrict__ W2,
                                                 const float* __restrict__ W3,
                                                 ushort* __restrict__ WTs1,
                                                 ushort* __restrict__ WTs2,
                                                 ushort* __restrict__ WTs3) {
    int y = blockIdx.y;
    const float* W = (y == 0) ? W1 : (y == 1) ? W2 : W3;
    ushort* WTs = (y == 0) ? WTs1 : (y == 1) ? WTs2 : WTs3;
    int K   = (y == 0) ? NPG : HID;
    int NKS = (y == 0) ? 3 : 8;
    int total = 4*NKS*4*64*8;                 // 256*Kp
    int idx = blockIdx.x*256 + threadIdx.x;
    if (idx >= total) return;
    int e    = idx & 7;
    int lane = (idx >> 3) & 63;
    int j    = (idx >> 9) & 3;
    int rest = idx >> 11;
    int ks   = rest % NKS;
    int fg   = rest / NKS;
    int row = fg*64 + j*16 + (lane & 15);     // 0..255
    int k   = ks*32 + (lane >> 4)*8 + e;      // 0..Kp-1
    WTs[idx] = (k < K) ? f2b(W[(size_t)k*HID + row]) : (ushort)0;
}

// ---- one GCN layer, fully LDS-resident (A served from LDS sA) ----
template<int NKS>
__device__ __forceinline__ void do_layer(ushort* buf,
                                         const ushort* __restrict__ WTs,
                                         const float* __restrict__ bias,
                                         const ushort* sA,
                                         float* sPool,
                                         int layer, int wave, int lane) {
    const int l15 = lane & 15, q = lane >> 4, lk = q*8;
    const int mg = wave >> 2, fg = wave & 3;

    // ---- S1: T = H @ W ----
    f32x4 acc1[3][4] = {};
    #pragma unroll
    for (int ks = 0; ks < NKS; ++ks) {
        bf16x8 af[3], bfr[4];
        #pragma unroll
        for (int i = 0; i < 3; ++i)
            af[i] = *(const bf16x8*)&buf[(mg*48 + i*16 + l15)*HSTR + ks*32 + lk];
        #pragma unroll
        for (int j = 0; j < 4; ++j)
            bfr[j] = *(const bf16x8*)&WTs[(size_t)(((fg*NKS + ks)*4 + j)*64 + lane)*8];
        #pragma unroll
        for (int i = 0; i < 3; ++i)
            #pragma unroll
            for (int j = 0; j < 4; ++j)
                acc1[i][j] = __builtin_amdgcn_mfma_f32_16x16x32_bf16(af[i], bfr[j], acc1[i][j], 0, 0, 0);
    }
    __syncthreads();   // (a) all h reads complete
    // ---- S2: write Tt[feat][node] over buf ----
    #pragma unroll
    for (int i = 0; i < 3; ++i)
        #pragma unroll
        for (int j = 0; j < 4; ++j)
            *(ushort4*)&buf[(fg*64 + j*16 + l15)*TSTR + mg*48 + i*16 + q*4] = cvt4(acc1[i][j]);
    __syncthreads();   // (b) Tt ready

    // ---- S3: E = A @ T (A fragments from LDS) ----
    f32x4 acc2[4][3] = {};
    #pragma unroll
    for (int ks = 0; ks < 3; ++ks) {
        bf16x8 af2[4], bf2[3];
        #pragma unroll
        for (int i = 0; i < 4; ++i)
            af2[i] = *(const bf16x8*)&buf[(fg*64 + i*16 + l15)*TSTR + ks*32 + lk];
        #pragma unroll
        for (int j = 0; j < 3; ++j)
            bf2[j] = *(const bf16x8*)&sA[(((mg*3 + ks)*3 + j)*64 + lane)*8];
        #pragma unroll
        for (int i = 0; i < 4; ++i)
            #pragma unroll
            for (int j = 0; j < 3; ++j)
                acc2[i][j] = __builtin_amdgcn_mfma_f32_16x16x32_bf16(af2[i], bf2[j], acc2[i][j], 0, 0, 0);
    }
    __syncthreads();   // (c) Tt reads complete

    // ---- S4: h = relu(E + b) over buf + pool partials into sPool ----
    const int loff = layer << 8;
    #pragma unroll
    for (int i = 0; i < 4; ++i) {
        int featb = fg*64 + i*16 + q*4;
        float4 bv = *(const float4*)&bias[featb];
        f32x4 psum = {};
        #pragma unroll
        for (int j = 0; j < 3; ++j) {
            int d = mg*48 + j*16 + l15;
            f32x4 v;
            v[0] = fmaxf(acc2[i][j][0] + bv.x, 0.f);
            v[1] = fmaxf(acc2[i][j][1] + bv.y, 0.f);
            v[2] = fmaxf(acc2[i][j][2] + bv.z, 0.f);
            v[3] = fmaxf(acc2[i][j][3] + bv.w, 0.f);
            if (d >= NPG) { v[0] = 0.f; v[1] = 0.f; v[2] = 0.f; v[3] = 0.f; }
            *(ushort4*)&buf[d*HSTR + featb] = cvt4(v);
            psum += v;
        }
        float s0 = psum[0], s1 = psum[1], s2 = psum[2], s3 = psum[3];
        #pragma unroll
        for (int m = 1; m < 16; m <<= 1) {
            s0 += __shfl_xor(s0, m); s1 += __shfl_xor(s1, m);
            s2 += __shfl_xor(s2, m); s3 += __shfl_xor(s3, m);
        }
        if (l15 == 0)
            *(float4*)&sPool[mg*EMBD + loff + featb] = make_float4(s0, s1, s2, s3);
    }
    __syncthreads();   // (d) h ready (Gram + next S1 read after this)
}

// ---- symmetric Gram: 21 upper-triangle tiles, consecutive ranges per wave ----
__device__ __forceinline__ void do_gram(const ushort* buf, int wave, int lane,
                                        f32x4 (&gacc)[3]) {
    const int l15 = lane & 15, lk = (lane >> 4)*8;
    const int start = (wave < 5) ? wave*3 : 15 + (wave - 5)*2;
    const int count = (wave < 5) ? 3 : 2;
    int ra0, rb0, ra1, rb1, ra2, rb2;
    unrank21(start,     ra0, rb0);
    unrank21(start + 1, ra1, rb1);
    unrank21(count > 2 ? start + 2 : start, ra2, rb2);  // dummy=slot0 if unused
    #pragma unroll
    for (int ks = 0; ks < 8; ++ks) {
        bf16x8 a0 = *(const bf16x8*)&buf[(ra0*16 + l15)*HSTR + ks*32 + lk];
        bf16x8 b0 = *(const bf16x8*)&buf[(rb0*16 + l15)*HSTR + ks*32 + lk];
        gacc[0] = __builtin_amdgcn_mfma_f32_16x16x32_bf16(a0, b0, gacc[0], 0, 0, 0);
        bf16x8 a1 = *(const bf16x8*)&buf[(ra1*16 + l15)*HSTR + ks*32 + lk];
        bf16x8 b1 = *(const bf16x8*)&buf[(rb1*16 + l15)*HSTR + ks*32 + lk];
        gacc[1] = __builtin_amdgcn_mfma_f32_16x16x32_bf16(a1, b1, gacc[1], 0, 0, 0);
        if (count > 2) {
            bf16x8 a2 = *(const bf16x8*)&buf[(ra2*16 + l15)*HSTR + ks*32 + lk];
            bf16x8 b2 = *(const bf16x8*)&buf[(rb2*16 + l15)*HSTR + ks*32 + lk];
            gacc[2] = __builtin_amdgcn_mfma_f32_16x16x32_bf16(a2, b2, gacc[2], 0, 0, 0);
        }
    }
}

// ---- mega kernel: buildA + 3 layers + pool/logits + decoder, one block per graph ----
__global__ __launch_bounds__(512, 4) void k_mega(const float* __restrict__ x,
                                                 const int* __restrict__ srcp,
                                                 const int* __restrict__ dstp,
                                                 const float* __restrict__ ew,
                                                 const ushort* __restrict__ WTs1,
                                                 const ushort* __restrict__ WTs2,
                                                 const ushort* __restrict__ WTs3,
                                                 const float* __restrict__ b1,
                                                 const float* __restrict__ b2,
                                                 const float* __restrict__ b3,
                                                 const float* __restrict__ Wc,
                                                 const float* __restrict__ bc,
                                                 float* __restrict__ outp) {
    extern __shared__ char lds[];
    ushort* buf   = (ushort*)lds;                               // 53248 B
    ushort* sA    = (ushort*)(lds + BUF_ELEMS*2);               // 18432 B
    float*  sPool = (float*)(lds + BUF_ELEMS*2 + SA_ELEMS*2);   // 6144 B
    const int g = blockIdx.x, tid = threadIdx.x;
    const int wave = tid >> 6, lane = tid & 63;
    const int l15 = lane & 15, q = lane >> 4;

    // ---- build A for this graph (deterministic int fixed-point), buf as scratch ----
    {
        int*   sAi   = (int*)buf;                 // 96*96 ints = 36864 B
        int*   sdegi = sAi + NPGP*NPGP;           // 96 ints
        float* sdi   = (float*)(sdegi + NPGP);    // 96 floats
        for (int i = tid; i < NPGP*NPGP; i += 512) sAi[i] = 0;
        if (tid < NPGP) sdegi[tid] = 0;
        const int base = g*NPG;
        int sl[3], dl[3]; float wv[3];
        #pragma unroll
        for (int it = 0; it < 3; ++it) {
            int eo = tid + it*512;
            bool valid = (eo < EPG);
            int e = g*EPG + (valid ? eo : 0);
            sl[it] = srcp[e] - base;
            dl[it] = dstp[e] - base;
            wv[it] = valid ? ew[e] : 0.f;
        }
        __syncthreads();
        #pragma unroll
        for (int it = 0; it < 3; ++it)
            atomicAdd(&sdegi[dl[it]], (int)rintf(wv[it]*1048576.0f));
        __syncthreads();
        if (tid < NPGP)
            sdi[tid] = rsqrtf(1.0f + (float)sdegi[tid]*(1.0f/1048576.0f));  // +1 self-loop
        __syncthreads();
        #pragma unroll
        for (int it = 0; it < 3; ++it) {
            float v = sdi[sl[it]]*wv[it]*sdi[dl[it]];
            atomicAdd(&sAi[dl[it]*NPGP + sl[it]], (int)rintf(v*16777216.0f));
        }
        __syncthreads();
        if (tid < NPG) {                   // diagonal self-loop term (single writer)
            float di = sdi[tid];
            sAi[tid*NPG + tid*(NPGP-NPG) + tid] += 0;  // no-op guard (kept simple below)
        }
        if (tid < NPG) {
            float di = sdi[tid];
            sAi[tid*NPGP + tid] += (int)rintf(di*di*16777216.0f);
        }
        __syncthreads();
        // convert into fragment-ordered bf16 sA (reads buf scratch, writes sA region)
        for (int i = tid; i < NPGP*NPGP; i += 512) {
            int e2   = i & 7;
            int ln   = (i >> 3) & 63;
            int t    = i >> 9;             // 0..17
            int jf   = t % 3;
            int ksf  = (t / 3) % 3;
            int mgf  = t / 9;
            int row = mgf*48 + jf*16 + (ln & 15);
            int col = ksf*32 + (ln >> 4)*8 + e2;
            sA[i] = f2b((float)sAi[row*NPGP + col]*(1.0f/16777216.0f));
        }
        __syncthreads();
    }

    // stage x into h-layout (rows 0..95 x cols 0..95, zero-padded) over buf scratch
    for (int idx = tid; idx < NPGP*NPGP; idx += 512) {
        int r = idx / NPGP, c = idx - r*NPGP;
        float v = (r < NPG && c < NPG) ? x[((size_t)g*NPG + r)*NPG + c] : 0.f;
        buf[r*HSTR + c] = f2b(v);
    }
    __syncthreads();

    f32x4 gacc[3] = {};

    do_layer<3>(buf, WTs1, b1, sA, sPool, 0, wave, lane);
    do_gram(buf, wave, lane, gacc);
    do_layer<8>(buf, WTs2, b2, sA, sPool, 1, wave, lane);
    do_gram(buf, wave, lane, gacc);
    do_layer<8>(buf, WTs3, b3, sA, sPool, 2, wave, lane);
    do_gram(buf, wave, lane, gacc);

    // ---- epilogue ----
    __syncthreads();                       // all Gram/S1 reads of buf complete
    float* fbuf = (float*)buf;             // adj staging [87][ASTRF] + reduce scratch
    {
        const int start = (wave < 5) ? wave*3 : 15 + (wave - 5)*2;
        const int count = (wave < 5) ? 3 : 2;
        #pragma unroll
        for (int s = 0; s < 3; ++s) {
            if (s < count) {
                int ti, tj;
                unrank21(start + s, ti, tj);
                int jj = tj*16 + l15;
                #pragma unroll
                for (int r = 0; r < 4; ++r) {
                    int ii = ti*16 + q*4 + r;
                    float v = fmaxf(gacc[s][r], 0.f);
                    if (ii < NPG && jj < NPG) {
                        fbuf[ii*ASTRF + jj] = v;
                        if (ti != tj) fbuf[jj*ASTRF + ii] = v;
                    }
                }
            }
        }
    }
    // logits partials (sPool stable since layer-3 barrier (d))
    float p0 = 0.f, p1 = 0.f;
    #pragma unroll
    for (int k2 = 0; k2 < 3; ++k2) {
        int c = tid + k2*512;
        int f = (c >= EMBD) ? c - EMBD : c;
        float v = sPool[c];
        p0 += v * Wc[f*2 + 0];
        p1 += v * Wc[f*2 + 1];
    }
    #pragma unroll
    for (int m = 1; m < 64; m <<= 1) { p0 += __shfl_xor(p0, m); p1 += __shfl_xor(p1, m); }
    if (lane == 0) { fbuf[8064 + wave*2] = p0; fbuf[8064 + wave*2 + 1] = p1; }
    __syncthreads();

    // coalesced adj copy-out (30.3 KB contiguous per graph)
    float* og = outp + (size_t)g*NPG*NPG;
    for (int idx = tid; idx < NPG*NPG; idx += 512) {
        int r = idx / NPG, cc = idx - r*NPG;
        og[idx] = fbuf[r*ASTRF + cc];
    }
    if (tid == 0) {
        float q0 = 0.f, q1 = 0.f;
        #pragma unroll
        for (int w = 0; w < 8; ++w) { q0 += fbuf[8064 + w*2]; q1 += fbuf[8064 + w*2 + 1]; }
        outp[ADJSZ + (size_t)g*2 + 0] = q0*(1.0f/87.0f) + bc[0];
        outp[ADJSZ + (size_t)g*2 + 1] = q1*(1.0f/87.0f) + bc[1];
    }
}

extern "C" void kernel_launch(void* const* d_in, const int* in_sizes, int n_in,
                              void* d_out, int out_size, void* d_ws, size_t ws_size,
                              hipStream_t stream) {
    const float* x   = (const float*)d_in[0];
    const int*   ei  = (const int*)d_in[1];
    const float* ew  = (const float*)d_in[2];
    const float* W1  = (const float*)d_in[4];
    const float* b1  = (const float*)d_in[5];
    const float* W2  = (const float*)d_in[6];
    const float* b2  = (const float*)d_in[7];
    const float* W3  = (const float*)d_in[8];
    const float* b3  = (const float*)d_in[9];
    const float* Wc  = (const float*)d_in[10];
    const float* bc  = (const float*)d_in[11];
    float* outp = (float*)d_out;

    char* ws = (char*)d_ws;
    ushort* WTs1 = (ushort*)ws;  ws += (size_t)HID*NPGP*2;
    ushort* WTs2 = (ushort*)ws;  ws += (size_t)HID*HID*2;
    ushort* WTs3 = (ushort*)ws;  ws += (size_t)HID*HID*2;

    const int* srcp = ei;
    const int* dstp = ei + NE;

    // allow >64KB dynamic LDS (host-side attribute, idempotent & deterministic)
    (void)hipFuncSetAttribute((const void*)k_mega,
                              hipFuncAttributeMaxDynamicSharedMemorySize, LDS_TOTAL);

    k_cast_wt<<<dim3(256,3), 256, 0, stream>>>(W1, W2, W3, WTs1, WTs2, WTs3);
    k_mega   <<<B_GRAPHS, 512, LDS_TOTAL, stream>>>(x, srcp, dstp, ew,
                                                    WTs1, WTs2, WTs3,
                                                    b1, b2, b3, Wc, bc, outp);
}

// Round 15
// 63.098 us; speedup vs baseline: 1.2950x; 1.0192x over previous
//
#include <hip/hip_runtime.h>
#include <hip/hip_bf16.h>

#define B_GRAPHS 512
#define NPG 87
#define NPGP 96
#define EPG 1392
#define NN (B_GRAPHS*NPG)        // 44544
#define NE (B_GRAPHS*EPG)        // 712704
#define HID 256
#define EMBD 768
#define ADJSZ (B_GRAPHS*NPG*NPG) // 3875328
#define HSTR 264                 // h layout stride (96 rows x 256 feats)
#define TSTR 104                 // Tt layout stride (256 rows x 96 nodes)
#define ASTRF 92                 // adj f32 staging stride
#define BUF_ELEMS 26624          // max(96*HSTR, 256*TSTR) ushorts = 53248 B
#define SA_ELEMS (NPGP*NPGP)     // 9216 ushorts = 18432 B
#define LDS_TOTAL (BUF_ELEMS*2 + SA_ELEMS*2 + 2*EMBD*4)   // 77824 B

typedef __attribute__((ext_vector_type(8))) short bf16x8;
typedef __attribute__((ext_vector_type(4))) float f32x4;

// native f32->bf16 (RNE); compiler pairs adjacent casts into v_cvt_pk_bf16_f32
__device__ __forceinline__ ushort f2b(float f) {
    __hip_bfloat16 h = __float2bfloat16(f);
    ushort u;
    __builtin_memcpy(&u, &h, 2);
    return u;
}
__device__ __forceinline__ ushort4 cvt4(f32x4 v) {
    ushort4 o; o.x = f2b(v[0]); o.y = f2b(v[1]); o.z = f2b(v[2]); o.w = f2b(v[3]);
    return o;
}

// upper-triangle tile rank t in [0,21) -> (i,j), i<=j<6
__device__ __forceinline__ void unrank21(int t, int& i, int& j) {
    i = (t >= 20) ? 5 : (t >= 18) ? 4 : (t >= 15) ? 3 : (t >= 11) ? 2 : (t >= 6) ? 1 : 0;
    int off = (i == 5) ? 20 : (i == 4) ? 18 : (i == 3) ? 15 : (i == 2) ? 11 : (i == 1) ? 6 : 0;
    j = i + (t - off);
}

// ---- W [K][256] f32 -> WTs in wave-fragment order ----
__global__ __launch_bounds__(256) void k_cast_wt(const float* __restrict__ W1,
                                                 const float* __restrict__ W2,
                                                 const float* __restrict__ W3,
                                                 ushort* __restrict__ WTs1,
                                                 ushort* __restrict__ WTs2,
                                                 ushort* __restrict__ WTs3) {
    int y = blockIdx.y;
    const float* W = (y == 0) ? W1 : (y == 1) ? W2 : W3;
    ushort* WTs = (y == 0) ? WTs1 : (y == 1) ? WTs2 : WTs3;
    int K   = (y == 0) ? NPG : HID;
    int NKS = (y == 0) ? 3 : 8;
    int total = 4*NKS*4*64*8;                 // 256*Kp
    int idx = blockIdx.x*256 + threadIdx.x;
    if (idx >= total) return;
    int e    = idx & 7;
    int lane = (idx >> 3) & 63;
    int j    = (idx >> 9) & 3;
    int rest = idx >> 11;
    int ks   = rest % NKS;
    int fg   = rest / NKS;
    int row = fg*64 + j*16 + (lane & 15);     // 0..255
    int k   = ks*32 + (lane >> 4)*8 + e;      // 0..Kp-1
    WTs[idx] = (k < K) ? f2b(W[(size_t)k*HID + row]) : (ushort)0;
}

// ---- one GCN layer, fully LDS-resident (A served from LDS sA) ----
template<int NKS>
__device__ __forceinline__ void do_layer(ushort* buf,
                                         const ushort* __restrict__ WTs,
                                         const float* __restrict__ bias,
                                         const ushort* sA,
                                         float* sPool,
                                         int layer, int wave, int lane) {
    const int l15 = lane & 15, q = lane >> 4, lk = q*8;
    const int mg = wave >> 2, fg = wave & 3;

    // ---- S1: T = H @ W ----
    f32x4 acc1[3][4] = {};
    #pragma unroll
    for (int ks = 0; ks < NKS; ++ks) {
        bf16x8 af[3], bfr[4];
        #pragma unroll
        for (int i = 0; i < 3; ++i)
            af[i] = *(const bf16x8*)&buf[(mg*48 + i*16 + l15)*HSTR + ks*32 + lk];
        #pragma unroll
        for (int j = 0; j < 4; ++j)
            bfr[j] = *(const bf16x8*)&WTs[(size_t)(((fg*NKS + ks)*4 + j)*64 + lane)*8];
        __builtin_amdgcn_s_setprio(1);
        #pragma unroll
        for (int i = 0; i < 3; ++i)
            #pragma unroll
            for (int j = 0; j < 4; ++j)
                acc1[i][j] = __builtin_amdgcn_mfma_f32_16x16x32_bf16(af[i], bfr[j], acc1[i][j], 0, 0, 0);
        __builtin_amdgcn_s_setprio(0);
    }
    __syncthreads();   // (a) all h reads complete
    // ---- S2: write Tt[feat][node] over buf ----
    #pragma unroll
    for (int i = 0; i < 3; ++i)
        #pragma unroll
        for (int j = 0; j < 4; ++j)
            *(ushort4*)&buf[(fg*64 + j*16 + l15)*TSTR + mg*48 + i*16 + q*4] = cvt4(acc1[i][j]);
    __syncthreads();   // (b) Tt ready

    // ---- S3: E = A @ T (A fragments from LDS) ----
    f32x4 acc2[4][3] = {};
    #pragma unroll
    for (int ks = 0; ks < 3; ++ks) {
        bf16x8 af2[4], bf2[3];
        #pragma unroll
        for (int i = 0; i < 4; ++i)
            af2[i] = *(const bf16x8*)&buf[(fg*64 + i*16 + l15)*TSTR + ks*32 + lk];
        #pragma unroll
        for (int j = 0; j < 3; ++j)
            bf2[j] = *(const bf16x8*)&sA[(((mg*3 + ks)*3 + j)*64 + lane)*8];
        __builtin_amdgcn_s_setprio(1);
        #pragma unroll
        for (int i = 0; i < 4; ++i)
            #pragma unroll
            for (int j = 0; j < 3; ++j)
                acc2[i][j] = __builtin_amdgcn_mfma_f32_16x16x32_bf16(af2[i], bf2[j], acc2[i][j], 0, 0, 0);
        __builtin_amdgcn_s_setprio(0);
    }
    __syncthreads();   // (c) Tt reads complete

    // ---- S4: h = relu(E + b) over buf + pool partials into sPool ----
    const int loff = layer << 8;
    #pragma unroll
    for (int i = 0; i < 4; ++i) {
        int featb = fg*64 + i*16 + q*4;
        float4 bv = *(const float4*)&bias[featb];
        f32x4 psum = {};
        #pragma unroll
        for (int j = 0; j < 3; ++j) {
            int d = mg*48 + j*16 + l15;
            f32x4 v;
            v[0] = fmaxf(acc2[i][j][0] + bv.x, 0.f);
            v[1] = fmaxf(acc2[i][j][1] + bv.y, 0.f);
            v[2] = fmaxf(acc2[i][j][2] + bv.z, 0.f);
            v[3] = fmaxf(acc2[i][j][3] + bv.w, 0.f);
            if (d >= NPG) { v[0] = 0.f; v[1] = 0.f; v[2] = 0.f; v[3] = 0.f; }
            *(ushort4*)&buf[d*HSTR + featb] = cvt4(v);
            psum += v;
        }
        float s0 = psum[0], s1 = psum[1], s2 = psum[2], s3 = psum[3];
        #pragma unroll
        for (int m = 1; m < 16; m <<= 1) {
            s0 += __shfl_xor(s0, m); s1 += __shfl_xor(s1, m);
            s2 += __shfl_xor(s2, m); s3 += __shfl_xor(s3, m);
        }
        if (l15 == 0)
            *(float4*)&sPool[mg*EMBD + loff + featb] = make_float4(s0, s1, s2, s3);
    }
    __syncthreads();   // (d) h ready (Gram + next S1 read after this)
}

// ---- symmetric Gram: 21 upper-triangle tiles, consecutive ranges per wave ----
__device__ __forceinline__ void do_gram(const ushort* buf, int wave, int lane,
                                        f32x4 (&gacc)[3]) {
    const int l15 = lane & 15, lk = (lane >> 4)*8;
    const int start = (wave < 5) ? wave*3 : 15 + (wave - 5)*2;
    const int count = (wave < 5) ? 3 : 2;
    int ra0, rb0, ra1, rb1, ra2, rb2;
    unrank21(start,     ra0, rb0);
    unrank21(start + 1, ra1, rb1);
    unrank21(count > 2 ? start + 2 : start, ra2, rb2);  // dummy=slot0 if unused
    #pragma unroll
    for (int ks = 0; ks < 8; ++ks) {
        bf16x8 a0 = *(const bf16x8*)&buf[(ra0*16 + l15)*HSTR + ks*32 + lk];
        bf16x8 b0 = *(const bf16x8*)&buf[(rb0*16 + l15)*HSTR + ks*32 + lk];
        bf16x8 a1 = *(const bf16x8*)&buf[(ra1*16 + l15)*HSTR + ks*32 + lk];
        bf16x8 b1 = *(const bf16x8*)&buf[(rb1*16 + l15)*HSTR + ks*32 + lk];
        __builtin_amdgcn_s_setprio(1);
        gacc[0] = __builtin_amdgcn_mfma_f32_16x16x32_bf16(a0, b0, gacc[0], 0, 0, 0);
        gacc[1] = __builtin_amdgcn_mfma_f32_16x16x32_bf16(a1, b1, gacc[1], 0, 0, 0);
        __builtin_amdgcn_s_setprio(0);
        if (count > 2) {
            bf16x8 a2 = *(const bf16x8*)&buf[(ra2*16 + l15)*HSTR + ks*32 + lk];
            bf16x8 b2 = *(const bf16x8*)&buf[(rb2*16 + l15)*HSTR + ks*32 + lk];
            __builtin_amdgcn_s_setprio(1);
            gacc[2] = __builtin_amdgcn_mfma_f32_16x16x32_bf16(a2, b2, gacc[2], 0, 0, 0);
            __builtin_amdgcn_s_setprio(0);
        }
    }
}

// ---- mega kernel: buildA + 3 layers + pool/logits + decoder, one block per graph ----
__global__ __launch_bounds__(512, 4) void k_mega(const float* __restrict__ x,
                                                 const int* __restrict__ srcp,
                                                 const int* __restrict__ dstp,
                                                 const float* __restrict__ ew,
                                                 const ushort* __restrict__ WTs1,
                                                 const ushort* __restrict__ WTs2,
                                                 const ushort* __restrict__ WTs3,
                                                 const float* __restrict__ b1,
                                                 const float* __restrict__ b2,
                                                 const float* __restrict__ b3,
                                                 const float* __restrict__ Wc,
                                                 const float* __restrict__ bc,
                                                 float* __restrict__ outp) {
    extern __shared__ char lds[];
    ushort* buf   = (ushort*)lds;                               // 53248 B
    ushort* sA    = (ushort*)(lds + BUF_ELEMS*2);               // 18432 B
    float*  sPool = (float*)(lds + BUF_ELEMS*2 + SA_ELEMS*2);   // 6144 B
    const int g = blockIdx.x, tid = threadIdx.x;
    const int wave = tid >> 6, lane = tid & 63;
    const int l15 = lane & 15, q = lane >> 4;

    // ---- build A for this graph (deterministic int fixed-point), buf as scratch ----
    {
        int*   sAi   = (int*)buf;                 // 96*96 ints = 36864 B
        int*   sdegi = sAi + NPGP*NPGP;           // 96 ints
        float* sdi   = (float*)(sdegi + NPGP);    // 96 floats
        for (int i = tid; i < NPGP*NPGP; i += 512) sAi[i] = 0;
        if (tid < NPGP) sdegi[tid] = 0;
        const int base = g*NPG;
        int sl[3], dl[3]; float wv[3];
        #pragma unroll
        for (int it = 0; it < 3; ++it) {
            int eo = tid + it*512;
            bool valid = (eo < EPG);
            int e = g*EPG + (valid ? eo : 0);
            sl[it] = srcp[e] - base;
            dl[it] = dstp[e] - base;
            wv[it] = valid ? ew[e] : 0.f;
        }
        __syncthreads();
        #pragma unroll
        for (int it = 0; it < 3; ++it)
            atomicAdd(&sdegi[dl[it]], (int)rintf(wv[it]*1048576.0f));
        __syncthreads();
        if (tid < NPGP)
            sdi[tid] = rsqrtf(1.0f + (float)sdegi[tid]*(1.0f/1048576.0f));  // +1 self-loop
        __syncthreads();
        #pragma unroll
        for (int it = 0; it < 3; ++it) {
            float v = sdi[sl[it]]*wv[it]*sdi[dl[it]];
            atomicAdd(&sAi[dl[it]*NPGP + sl[it]], (int)rintf(v*16777216.0f));
        }
        __syncthreads();
        if (tid < NPG) {                   // diagonal self-loop term (single writer)
            float di = sdi[tid];
            sAi[tid*NPGP + tid] += (int)rintf(di*di*16777216.0f);
        }
        __syncthreads();
        // convert into fragment-ordered bf16 sA (reads buf scratch, writes sA region)
        for (int i = tid; i < NPGP*NPGP; i += 512) {
            int e2   = i & 7;
            int ln   = (i >> 3) & 63;
            int t    = i >> 9;             // 0..17
            int jf   = t % 3;
            int ksf  = (t / 3) % 3;
            int mgf  = t / 9;
            int row = mgf*48 + jf*16 + (ln & 15);
            int col = ksf*32 + (ln >> 4)*8 + e2;
            sA[i] = f2b((float)sAi[row*NPGP + col]*(1.0f/16777216.0f));
        }
        __syncthreads();
    }

    // stage x into h-layout (rows 0..95 x cols 0..95, zero-padded) over buf scratch
    for (int idx = tid; idx < NPGP*NPGP; idx += 512) {
        int r = idx / NPGP, c = idx - r*NPGP;
        float v = (r < NPG && c < NPG) ? x[((size_t)g*NPG + r)*NPG + c] : 0.f;
        buf[r*HSTR + c] = f2b(v);
    }
    __syncthreads();

    f32x4 gacc[3] = {};

    do_layer<3>(buf, WTs1, b1, sA, sPool, 0, wave, lane);
    do_gram(buf, wave, lane, gacc);
    do_layer<8>(buf, WTs2, b2, sA, sPool, 1, wave, lane);
    do_gram(buf, wave, lane, gacc);
    do_layer<8>(buf, WTs3, b3, sA, sPool, 2, wave, lane);
    do_gram(buf, wave, lane, gacc);

    // ---- epilogue ----
    __syncthreads();                       // all Gram/S1 reads of buf complete
    float* fbuf = (float*)buf;             // adj staging [87][ASTRF] + reduce scratch
    {
        const int start = (wave < 5) ? wave*3 : 15 + (wave - 5)*2;
        const int count = (wave < 5) ? 3 : 2;
        #pragma unroll
        for (int s = 0; s < 3; ++s) {
            if (s < count) {
                int ti, tj;
                unrank21(start + s, ti, tj);
                int jj = tj*16 + l15;
                #pragma unroll
                for (int r = 0; r < 4; ++r) {
                    int ii = ti*16 + q*4 + r;
                    float v = fmaxf(gacc[s][r], 0.f);
                    if (ii < NPG && jj < NPG) {
                        fbuf[ii*ASTRF + jj] = v;
                        if (ti != tj) fbuf[jj*ASTRF + ii] = v;
                    }
                }
            }
        }
    }
    // logits partials (sPool stable since layer-3 barrier (d))
    float p0 = 0.f, p1 = 0.f;
    #pragma unroll
    for (int k2 = 0; k2 < 3; ++k2) {
        int c = tid + k2*512;
        int f = (c >= EMBD) ? c - EMBD : c;
        float v = sPool[c];
        p0 += v * Wc[f*2 + 0];
        p1 += v * Wc[f*2 + 1];
    }
    #pragma unroll
    for (int m = 1; m < 64; m <<= 1) { p0 += __shfl_xor(p0, m); p1 += __shfl_xor(p1, m); }
    if (lane == 0) { fbuf[8064 + wave*2] = p0; fbuf[8064 + wave*2 + 1] = p1; }
    __syncthreads();

    // coalesced adj copy-out (30.3 KB contiguous per graph)
    float* og = outp + (size_t)g*NPG*NPG;
    for (int idx = tid; idx < NPG*NPG; idx += 512) {
        int r = idx / NPG, cc = idx - r*NPG;
        og[idx] = fbuf[r*ASTRF + cc];
    }
    if (tid == 0) {
        float q0 = 0.f, q1 = 0.f;
        #pragma unroll
        for (int w = 0; w < 8; ++w) { q0 += fbuf[8064 + w*2]; q1 += fbuf[8064 + w*2 + 1]; }
        outp[ADJSZ + (size_t)g*2 + 0] = q0*(1.0f/87.0f) + bc[0];
        outp[ADJSZ + (size_t)g*2 + 1] = q1*(1.0f/87.0f) + bc[1];
    }
}

extern "C" void kernel_launch(void* const* d_in, const int* in_sizes, int n_in,
                              void* d_out, int out_size, void* d_ws, size_t ws_size,
                              hipStream_t stream) {
    const float* x   = (const float*)d_in[0];
    const int*   ei  = (const int*)d_in[1];
    const float* ew  = (const float*)d_in[2];
    const float* W1  = (const float*)d_in[4];
    const float* b1  = (const float*)d_in[5];
    const float* W2  = (const float*)d_in[6];
    const float* b2  = (const float*)d_in[7];
    const float* W3  = (const float*)d_in[8];
    const float* b3  = (const float*)d_in[9];
    const float* Wc  = (const float*)d_in[10];
    const float* bc  = (const float*)d_in[11];
    float* outp = (float*)d_out;

    char* ws = (char*)d_ws;
    ushort* WTs1 = (ushort*)ws;  ws += (size_t)HID*NPGP*2;
    ushort* WTs2 = (ushort*)ws;  ws += (size_t)HID*HID*2;
    ushort* WTs3 = (ushort*)ws;  ws += (size_t)HID*HID*2;

    const int* srcp = ei;
    const int* dstp = ei + NE;

    // allow >64KB dynamic LDS (host-side attribute, idempotent & deterministic)
    (void)hipFuncSetAttribute((const void*)k_mega,
                              hipFuncAttributeMaxDynamicSharedMemorySize, LDS_TOTAL);

    k_cast_wt<<<dim3(256,3), 256, 0, stream>>>(W1, W2, W3, WTs1, WTs2, WTs3);
    k_mega   <<<B_GRAPHS, 512, LDS_TOTAL, stream>>>(x, srcp, dstp, ew,
                                                    WTs1, WTs2, WTs3,
                                                    b1, b2, b3, Wc, bc, outp);
}